// Round 16
// baseline (139.259 us; speedup 1.0000x reference)
//
#include <hip/hip_runtime.h>
#include <hip/hip_bf16.h>
#include <cstdint>

#define NHEADS 16
#define HDIM 64
#define BB 2
#define TSEQ 2048
#define DM 1024
#define MROWS (BB*TSEQ)   // 4096

typedef unsigned short u16;
typedef unsigned int u32;
typedef __bf16 bf16x8 __attribute__((ext_vector_type(8)));
typedef float f32x4 __attribute__((ext_vector_type(4)));

#define AS1C(p) ((const __attribute__((address_space(1))) u32*)(p))
#define AS3(p)  ((__attribute__((address_space(3))) u32*)(p))

static __device__ __forceinline__ u16 f2bf(float f) {
  return __builtin_bit_cast(u16, __float2bfloat16(f));
}
static __device__ __forceinline__ float bf2f(u16 u) {
  return __bfloat162float(__builtin_bit_cast(__hip_bfloat16, u));
}
// pack two non-NaN floats to bf16 pair (round-half-up, max rel err 2^-8)
static __device__ __forceinline__ u32 pack2bf(float a, float b) {
  const u32 ua = __builtin_bit_cast(u32, a) + 0x8000u;
  const u32 ub = __builtin_bit_cast(u32, b) + 0x8000u;
  return (ua >> 16) | (ub & 0xFFFF0000u);
}
static __device__ __forceinline__ f32x4 mfma16x16(bf16x8 a, bf16x8 b, f32x4 c) {
  return __builtin_amdgcn_mfma_f32_16x16x32_bf16(a, b, c, 0, 0, 0);
}

// ---------------- fused cast fp32 -> bf16 for x, W_qkv, W_o ----------------
#define N4_X   (MROWS * DM / 4)
#define N4_WQ  (3 * DM * DM / 4)
#define N4_WO  (DM * DM / 4)
__global__ __launch_bounds__(256) void cast_all(const float* __restrict__ x,
                                                const float* __restrict__ wq,
                                                const float* __restrict__ wo,
                                                u16* __restrict__ xb,
                                                u16* __restrict__ wqb,
                                                u16* __restrict__ wob) {
  int i = blockIdx.x * 256 + threadIdx.x;
  const int stride = gridDim.x * 256;
  for (; i < N4_X + N4_WQ + N4_WO; i += stride) {
    const float4* src; u16* dst; int j;
    if (i < N4_X)            { src = (const float4*)x;  dst = xb;  j = i; }
    else if (i < N4_X + N4_WQ) { src = (const float4*)wq; dst = wqb; j = i - N4_X; }
    else                     { src = (const float4*)wo; dst = wob; j = i - N4_X - N4_WQ; }
    float4 v = src[j];
    ushort4 o;
    o.x = f2bf(v.x); o.y = f2bf(v.y); o.z = f2bf(v.z); o.w = f2bf(v.w);
    ((ushort4*)dst)[j] = o;
  }
}

// ------- GEMM1 fused: qkv = x @ Wqkv^T, epilogue does RoPE + reshape -------
__global__ __launch_bounds__(256, 2) void gemm_qkv(const u16* __restrict__ A,
                                                   const u16* __restrict__ Bm,
                                                   u16* __restrict__ qb,
                                                   u16* __restrict__ kbuf,
                                                   u16* __restrict__ vbT,
                                                   int M, int N, int K) {
  __shared__ u16 lA[2][128 * 32];
  __shared__ u16 lB[2][128 * 32];
  const int tid = threadIdx.x;
  const int w = tid >> 6, l = tid & 63;
  const int wr = w >> 1, wc = w & 1;
  int bid = blockIdx.y * gridDim.x + blockIdx.x;
  const int cpx = (gridDim.x * gridDim.y) >> 3;
  bid = (bid & 7) * cpx + (bid >> 3);
  const int bx = bid % gridDim.x, by = bid / gridDim.x;
  const int brow = by * 128, bcol = bx * 128;
  const int lr = l & 15, lg = l >> 4;
  const bool isqk = (bcol < 2048);

  const int srow = l >> 2;
  const int scol = (((l & 3) ^ (srow & 3)) * 8);

  auto stage = [&](int buf, int k0) {
#pragma unroll
    for (int is = 0; is < 2; ++is) {
      const int chunk = w * 2 + is;
      const int row = chunk * 16 + srow;
      __builtin_amdgcn_global_load_lds(AS1C(A + (size_t)(brow + row) * K + k0 + scol),
                                       AS3((char*)lA[buf] + chunk * 1024), 16, 0, 0);
      int prow = row;
      if (isqk) {
        const int r63 = row & 63;
        prow = (row & 64) | ((r63 < 32) ? (2 * r63) : (2 * (r63 - 32) + 1));
      }
      __builtin_amdgcn_global_load_lds(AS1C(Bm + (size_t)(bcol + prow) * K + k0 + scol),
                                       AS3((char*)lB[buf] + chunk * 1024), 16, 0, 0);
    }
  };

  f32x4 acc[4][4] = {};
  const int nk = K >> 5;
  stage(0, 0);
  for (int kk = 0; kk < nk; ++kk) {
    const int cur = kk & 1;
    __syncthreads();
    if (kk + 1 < nk) stage(cur ^ 1, (kk + 1) << 5);
    bf16x8 af[4], bfr[4];
#pragma unroll
    for (int m = 0; m < 4; ++m) {
      const int row = wr * 64 + m * 16 + lr;
      const int sl = lg ^ (row & 3);
      af[m] = *(const bf16x8*)(&lA[cur][row * 32 + sl * 8]);
    }
#pragma unroll
    for (int n = 0; n < 4; ++n) {
      const int row = wc * 64 + n * 16 + lr;
      const int sl = lg ^ (row & 3);
      bfr[n] = *(const bf16x8*)(&lB[cur][row * 32 + sl * 8]);
    }
#pragma unroll
    for (int m = 0; m < 4; ++m)
#pragma unroll
      for (int n = 0; n < 4; ++n)
        acc[m][n] = mfma16x16(af[m], bfr[n], acc[m][n]);
  }

  const float C = -0.4152410118609203f;   // -log2(10000)/32
  const float QS = 0.125f * 1.44269504088896341f;
  const float R2PI = 0.15915494309189535f;

  if (isqk) {          // q or k block: register-local RoPE pair
    const bool isq = (bcol < 1024);
    const int head = ((bcol + wc * 64) >> 6) & 15;
    u16* dst = isq ? qb : kbuf;
#pragma unroll
    for (int n = 0; n < 2; ++n) {
      const int p = n * 16 + lr;          // pair index; d = 2p
      const float inv = exp2f((float)p * C);
#pragma unroll
      for (int m = 0; m < 4; ++m)
#pragma unroll
        for (int r = 0; r < 4; ++r) {
          const int row = brow + wr * 64 + m * 16 + lg * 4 + r;
          const int t = row & (TSEQ - 1), b = row >> 11;
          const float rev = __builtin_amdgcn_fractf((float)t * inv * R2PI);
          float sn = __builtin_amdgcn_sinf(rev);
          float cs = __builtin_amdgcn_cosf(rev);
          if (isq) { sn *= QS; cs *= QS; }
          const float e = acc[m][n][r];     // even d = 2p
          const float o = acc[m][n + 2][r]; // odd  d = 2p+1
          const u32 pk = pack2bf(e * cs - o * sn, e * sn + o * cs);
          *(u32*)(&dst[(((size_t)(b * 16 + head)) * TSEQ + t) * 64 + 2 * p]) = pk;
        }
    }
  } else {             // v block: transposed write to vbT[bh][64][TSEQ]
    const int head = (((bcol - 2048) + wc * 64) >> 6) & 15;
#pragma unroll
    for (int n = 0; n < 4; ++n) {
      const int d = n * 16 + lr;
#pragma unroll
      for (int m = 0; m < 4; ++m) {
        const int row0 = brow + wr * 64 + m * 16 + lg * 4;
        const int t = row0 & (TSEQ - 1), b = row0 >> 11;
        uint2 pk;
        pk.x = pack2bf(acc[m][n][0], acc[m][n][1]);
        pk.y = pack2bf(acc[m][n][2], acc[m][n][3]);
        *(uint2*)(&vbT[((size_t)(b * 16 + head) * 64 + d) * TSEQ + t]) = pk;
      }
    }
  }
}

// ------------- bf16 GEMM 64x128 tile (fp32 out) — output projection --------
__global__ __launch_bounds__(256, 2) void gemm_bt64(const u16* __restrict__ A,
                                                    const u16* __restrict__ Bm,
                                                    float* __restrict__ Cf,
                                                    int M, int N, int K) {
  __shared__ u16 lA[2][64 * 32];
  __shared__ u16 lB[2][128 * 32];
  const int tid = threadIdx.x;
  const int w = tid >> 6, l = tid & 63;
  const int wr = w >> 1, wc = w & 1;
  int bid = blockIdx.y * gridDim.x + blockIdx.x;
  const int cpx = (gridDim.x * gridDim.y) >> 3;
  bid = (bid & 7) * cpx + (bid >> 3);
  const int bx = bid % gridDim.x, by = bid / gridDim.x;
  const int brow = by * 64, bcol = bx * 128;
  const int lr = l & 15, lg = l >> 4;

  const int srow = l >> 2;
  const int scol = (((l & 3) ^ (srow & 3)) * 8);

  auto stage = [&](int buf, int k0) {
    {
      const int row = w * 16 + srow;
      __builtin_amdgcn_global_load_lds(AS1C(A + (size_t)(brow + row) * K + k0 + scol),
                                       AS3((char*)lA[buf] + w * 1024), 16, 0, 0);
    }
#pragma unroll
    for (int is = 0; is < 2; ++is) {
      const int chunk = w * 2 + is;
      const int row = chunk * 16 + srow;
      __builtin_amdgcn_global_load_lds(AS1C(Bm + (size_t)(bcol + row) * K + k0 + scol),
                                       AS3((char*)lB[buf] + chunk * 1024), 16, 0, 0);
    }
  };

  f32x4 acc[2][4] = {};
  const int nk = K >> 5;
  stage(0, 0);
  for (int kk = 0; kk < nk; ++kk) {
    const int cur = kk & 1;
    __syncthreads();
    if (kk + 1 < nk) stage(cur ^ 1, (kk + 1) << 5);
    bf16x8 af[2], bfr[4];
#pragma unroll
    for (int m = 0; m < 2; ++m) {
      const int row = wr * 32 + m * 16 + lr;
      const int sl = lg ^ (row & 3);
      af[m] = *(const bf16x8*)(&lA[cur][row * 32 + sl * 8]);
    }
#pragma unroll
    for (int n = 0; n < 4; ++n) {
      const int row = wc * 64 + n * 16 + lr;
      const int sl = lg ^ (row & 3);
      bfr[n] = *(const bf16x8*)(&lB[cur][row * 32 + sl * 8]);
    }
#pragma unroll
    for (int m = 0; m < 2; ++m)
#pragma unroll
      for (int n = 0; n < 4; ++n)
        acc[m][n] = mfma16x16(af[m], bfr[n], acc[m][n]);
  }
#pragma unroll
  for (int m = 0; m < 2; ++m)
#pragma unroll
    for (int n = 0; n < 4; ++n)
#pragma unroll
      for (int r = 0; r < 4; ++r) {
        const int row = brow + wr * 32 + m * 16 + lg * 4 + r;
        const int col = bcol + wc * 64 + n * 16 + lr;
        Cf[(size_t)row * N + col] = acc[m][n][r];
      }
}

// ---------------- causal flash attention (R5 structure, T14 async-split) ---
// Identical tiling/barriers to the proven R5 config, but K/V staging goes
// global->REG (issued right after the barrier) and LDS-write happens at the
// END of the compute phase into the free buffer. At each __syncthreads the
// outstanding VMEM count is ZERO (loads already consumed), so the compiler's
// mandatory vmcnt(0)-drain at the barrier is free; only cheap lgkm remains.
__global__ __launch_bounds__(512, 4) void attn_fwd(const u16* __restrict__ qb,
                                                   const u16* __restrict__ kb,
                                                   const u16* __restrict__ vbT,
                                                   u16* __restrict__ ob) {
  __shared__ u16 lK[4][64 * 64];
  __shared__ u16 lV[4][64 * 64];
  __shared__ u16 lP[8][16 * 64];
  const int hw = blockIdx.x;
  const int logical = (hw & 7) * 64 + (hw >> 3);  // 8 XCDs x 64 blocks
  const int bh = logical >> 4;            // 4 consecutive heads per XCD
  const int pair = logical & 15;
  const int b = bh >> 4, h = bh & 15;
  const int tid = threadIdx.x;
  const int w = tid >> 6, l = tid & 63;
  const int g = w >> 2, wq = w & 3;       // kv-group, q-wave within group
  const int lr = l & 15, lg = l >> 4;
  const int srow8 = l >> 3;
  const int scol = ((l & 7) ^ srow8) * 8; // pre-swizzled source col (elems)
  const u16* Kb = kb + (size_t)bh * TSEQ * 64;
  const u16* Vb = vbT + (size_t)bh * 64 * TSEQ;
  u16* lPw = lP[w];

  uint4 kreg[2], vreg[2];                 // staged next tile (reg, 16 VGPR)
  auto issueLoads = [&](int kt) {
#pragma unroll
    for (int is = 0; is < 2; ++is) {
      const int chunk = wq * 2 + is;            // 0..7
      const int row = chunk * 8 + srow8;        // 0..63
      kreg[is] = *(const uint4*)(Kb + (size_t)(kt * 64 + row) * 64 + scol);
      vreg[is] = *(const uint4*)(Vb + (size_t)row * TSEQ + kt * 64 + scol);
    }
  };
  auto writeLDS = [&](int buf) {
#pragma unroll
    for (int is = 0; is < 2; ++is) {
      const int chunk = wq * 2 + is;
      *(uint4*)((char*)lK[g * 2 + buf] + chunk * 1024 + l * 16) = kreg[is];
      *(uint4*)((char*)lV[g * 2 + buf] + chunk * 1024 + l * 16) = vreg[is];
    }
  };

  for (int half = 0; half < 2; ++half) {
    const int qt = half ? (TSEQ / 64 - 1 - pair) : pair;
    const int q0 = qt * 64;

    bf16x8 qf[2];
    {
      const u16* qp = qb + ((size_t)bh * TSEQ + q0 + wq * 16 + lr) * 64 + lg * 8;
      qf[0] = *(const bf16x8*)qp;
      qf[1] = *(const bf16x8*)(qp + 32);
    }

    f32x4 oacc[4] = {};
    float lsum = 0.f;

    const int nt = qt + 1;
    const int nit = (nt + 1) >> 1;
    const int ql = wq * 16 + lr;

    __syncthreads();                 // prev half's merge reads done; LDS free
    if (g < nt) { issueLoads(g); writeLDS(0); }
    for (int it = 0; it < nit; ++it) {
      const int cur = it & 1;
      __syncthreads();               // buf[cur] writes (end of prev iter) visible
      const int ktn = 2 * (it + 1) + g;
      if (ktn < nt) issueLoads(ktn);       // global -> regs; consumed below
      const int kt = 2 * it + g;
      if (kt < nt) {
        const u16* Kc = lK[g * 2 + cur];
        const u16* Vc = lV[g * 2 + cur];

        // S^T = K Q^T: lane holds S[q=lr][kv = n*16 + lg*4 + r] (log2 domain)
        f32x4 s[4] = {};
        __builtin_amdgcn_s_setprio(1);
#pragma unroll
        for (int n = 0; n < 4; ++n) {
          const int row = n * 16 + lr;
#pragma unroll
          for (int ks = 0; ks < 2; ++ks) {
            const int sl = (ks * 4 + lg) ^ (row & 7);
            bf16x8 kf = *(const bf16x8*)(&Kc[row * 64 + sl * 8]);
            s[n] = mfma16x16(kf, qf[ks], s[n]);
          }
        }
        __builtin_amdgcn_s_setprio(0);

        // P = exp2(s) raw; masked entries zeroed; per-lane partial sums.
        const bool diag = (kt == qt);
#pragma unroll
        for (int n = 0; n < 4; ++n) {
          float pv[4];
#pragma unroll
          for (int r = 0; r < 4; ++r) {
            float p = __builtin_amdgcn_exp2f(s[n][r]);
            if (diag && (n * 16 + lg * 4 + r > ql)) p = 0.f;
            pv[r] = p;
            lsum += p;
          }
          const u32 w0 = pack2bf(pv[0], pv[1]);
          const u32 w1 = pack2bf(pv[2], pv[3]);
          const int phys = (n * 2 + (lg >> 1)) ^ (lr & 7);
          uint2 pk; pk.x = w0; pk.y = w1;
          *(uint2*)(&lPw[lr * 64 + phys * 8 + (lg & 1) * 4]) = pk;
        }

        // O^T += V P^T: lane holds O[q=lr][d = n*16 + lg*4 + r]
        bf16x8 pf[2];
#pragma unroll
        for (int ks = 0; ks < 2; ++ks) {
          const int phys = (ks * 4 + lg) ^ (lr & 7);
          pf[ks] = *(const bf16x8*)(&lPw[lr * 64 + phys * 8]);
        }
        __builtin_amdgcn_s_setprio(1);
#pragma unroll
        for (int n = 0; n < 4; ++n) {
          const int row = n * 16 + lr;
#pragma unroll
          for (int ks = 0; ks < 2; ++ks) {
            const int sl = (ks * 4 + lg) ^ (row & 7);
            bf16x8 vf = *(const bf16x8*)(&Vc[row * 64 + sl * 8]);
            oacc[n] = mfma16x16(vf, pf[ks], oacc[n]);
          }
        }
        __builtin_amdgcn_s_setprio(0);
      }
      // write-late: next tile's data into the free buffer (readers of
      // buf[cur^1] all passed this iter's barrier already)
      if (ktn < nt) writeLDS(cur ^ 1);
    }

    // row-total of this group's partial sums (single reduction per q-tile)
    lsum += __shfl_xor(lsum, 16);
    lsum += __shfl_xor(lsum, 32);

    // merge the two groups' (O, l) through LDS — no exp scaling needed
    __syncthreads();                  // all compute done; K/V LDS reusable
    float* mO = (float*)&lK[0][0];    // 4 waves x 1024 f32 = 16KB
    float* mL = (float*)&lV[0][0];    // 4 waves x 16 f32
    if (g == 1) {
#pragma unroll
      for (int n = 0; n < 4; ++n)
#pragma unroll
        for (int r = 0; r < 4; ++r) {
          const int d = n * 16 + lg * 4 + r;
          mO[wq * 1024 + d * 16 + lr] = oacc[n][r];
        }
      if (lg == 0) mL[wq * 16 + lr] = lsum;
    }
    __syncthreads();
    if (g == 0) {
      const float rl = 1.f / (lsum + mL[wq * 16 + lr]);
      const int q = q0 + wq * 16 + lr;
#pragma unroll
      for (int n = 0; n < 4; ++n) {
        ushort4 ov;
#pragma unroll
        for (int r = 0; r < 4; ++r) {
          const int d = n * 16 + lg * 4 + r;
          const float o = oacc[n][r] + mO[wq * 1024 + d * 16 + lr];
          ((u16*)&ov)[r] = f2bf(o * rl);
        }
        *(ushort4*)(&ob[(size_t)(b * TSEQ + q) * DM + h * 64 + n * 16 + lg * 4]) = ov;
      }
    }
  }
}

// ---------------- launch ----------------
extern "C" void kernel_launch(void* const* d_in, const int* in_sizes, int n_in,
                              void* d_out, int out_size, void* d_ws, size_t ws_size,
                              hipStream_t stream) {
  const float* x    = (const float*)d_in[0];
  const float* Wqkv = (const float*)d_in[1];
  const float* Wo   = (const float*)d_in[2];
  float* out = (float*)d_out;

  char* ws = (char*)d_ws;
  u16* xb    = (u16*)ws; ws += (size_t)MROWS * DM * 2;
  u16* wqkvb = (u16*)ws; ws += (size_t)3 * DM * DM * 2;
  u16* wob   = (u16*)ws; ws += (size_t)DM * DM * 2;
  u16* qb    = (u16*)ws; ws += (size_t)BB * NHEADS * TSEQ * HDIM * 2;
  u16* kb    = (u16*)ws; ws += (size_t)BB * NHEADS * TSEQ * HDIM * 2;
  u16* vbT   = (u16*)ws; ws += (size_t)BB * NHEADS * TSEQ * HDIM * 2;
  u16* ob    = (u16*)ws; ws += (size_t)MROWS * DM * 2;

  cast_all<<<2048, 256, 0, stream>>>(x, Wqkv, Wo, xb, wqkvb, wob);

  gemm_qkv<<<dim3(3 * DM / 128, MROWS / 128), 256, 0, stream>>>(
      xb, wqkvb, qb, kb, vbT, MROWS, 3 * DM, DM);

  attn_fwd<<<512, 512, 0, stream>>>(qb, kb, vbT, ob);

  gemm_bt64<<<dim3(DM / 128, MROWS / 64), 256, 0, stream>>>(
      ob, wob, out, MROWS, DM, DM);
}

// Round 17
// 98.282 us; speedup vs baseline: 1.4169x; 1.4169x over previous
//
#include <hip/hip_runtime.h>
#include <hip/hip_bf16.h>
#include <cstdint>

#define NHEADS 16
#define HDIM 64
#define BB 2
#define TSEQ 2048
#define DM 1024
#define MROWS (BB*TSEQ)   // 4096

typedef unsigned short u16;
typedef unsigned int u32;
typedef __bf16 bf16x8 __attribute__((ext_vector_type(8)));
typedef float f32x4 __attribute__((ext_vector_type(4)));

#define AS1C(p) ((const __attribute__((address_space(1))) u32*)(p))
#define AS3(p)  ((__attribute__((address_space(3))) u32*)(p))

static __device__ __forceinline__ u16 f2bf(float f) {
  return __builtin_bit_cast(u16, __float2bfloat16(f));
}
static __device__ __forceinline__ float bf2f(u16 u) {
  return __bfloat162float(__builtin_bit_cast(__hip_bfloat16, u));
}
// pack two non-NaN floats to bf16 pair (round-half-up, max rel err 2^-8)
static __device__ __forceinline__ u32 pack2bf(float a, float b) {
  const u32 ua = __builtin_bit_cast(u32, a) + 0x8000u;
  const u32 ub = __builtin_bit_cast(u32, b) + 0x8000u;
  return (ua >> 16) | (ub & 0xFFFF0000u);
}
static __device__ __forceinline__ f32x4 mfma16x16(bf16x8 a, bf16x8 b, f32x4 c) {
  return __builtin_amdgcn_mfma_f32_16x16x32_bf16(a, b, c, 0, 0, 0);
}

// ---------------- fused cast fp32 -> bf16 for x, W_qkv, W_o ----------------
#define N4_X   (MROWS * DM / 4)
#define N4_WQ  (3 * DM * DM / 4)
#define N4_WO  (DM * DM / 4)
__global__ __launch_bounds__(256) void cast_all(const float* __restrict__ x,
                                                const float* __restrict__ wq,
                                                const float* __restrict__ wo,
                                                u16* __restrict__ xb,
                                                u16* __restrict__ wqb,
                                                u16* __restrict__ wob) {
  int i = blockIdx.x * 256 + threadIdx.x;
  const int stride = gridDim.x * 256;
  for (; i < N4_X + N4_WQ + N4_WO; i += stride) {
    const float4* src; u16* dst; int j;
    if (i < N4_X)            { src = (const float4*)x;  dst = xb;  j = i; }
    else if (i < N4_X + N4_WQ) { src = (const float4*)wq; dst = wqb; j = i - N4_X; }
    else                     { src = (const float4*)wo; dst = wob; j = i - N4_X - N4_WQ; }
    float4 v = src[j];
    ushort4 o;
    o.x = f2bf(v.x); o.y = f2bf(v.y); o.z = f2bf(v.z); o.w = f2bf(v.w);
    ((ushort4*)dst)[j] = o;
  }
}

// ------- GEMM1 fused: qkv = x @ Wqkv^T, epilogue does RoPE + reshape -------
// 128x128 tile, 2-phase double-buffer. B-rows permuted at the staging source
// for q/k blocks so the RoPE pair (2p,2p+1) is register-local (frag n, n+2).
// launch_bounds(256,4): grid is 768 blocks = 3/CU; allowing 4 waves/SIMD
// lets all 3 co-reside (12 waves/CU) to hide the per-iter barrier drains.
__global__ __launch_bounds__(256, 4) void gemm_qkv(const u16* __restrict__ A,
                                                   const u16* __restrict__ Bm,
                                                   u16* __restrict__ qb,
                                                   u16* __restrict__ kbuf,
                                                   u16* __restrict__ vbT,
                                                   int M, int N, int K) {
  __shared__ u16 lA[2][128 * 32];
  __shared__ u16 lB[2][128 * 32];
  const int tid = threadIdx.x;
  const int w = tid >> 6, l = tid & 63;
  const int wr = w >> 1, wc = w & 1;
  int bid = blockIdx.y * gridDim.x + blockIdx.x;
  const int cpx = (gridDim.x * gridDim.y) >> 3;
  bid = (bid & 7) * cpx + (bid >> 3);
  const int bx = bid % gridDim.x, by = bid / gridDim.x;
  const int brow = by * 128, bcol = bx * 128;
  const int lr = l & 15, lg = l >> 4;
  const bool isqk = (bcol < 2048);

  const int srow = l >> 2;
  const int scol = (((l & 3) ^ (srow & 3)) * 8);

  auto stage = [&](int buf, int k0) {
#pragma unroll
    for (int is = 0; is < 2; ++is) {
      const int chunk = w * 2 + is;
      const int row = chunk * 16 + srow;
      __builtin_amdgcn_global_load_lds(AS1C(A + (size_t)(brow + row) * K + k0 + scol),
                                       AS3((char*)lA[buf] + chunk * 1024), 16, 0, 0);
      int prow = row;
      if (isqk) {
        const int r63 = row & 63;
        prow = (row & 64) | ((r63 < 32) ? (2 * r63) : (2 * (r63 - 32) + 1));
      }
      __builtin_amdgcn_global_load_lds(AS1C(Bm + (size_t)(bcol + prow) * K + k0 + scol),
                                       AS3((char*)lB[buf] + chunk * 1024), 16, 0, 0);
    }
  };

  f32x4 acc[4][4] = {};
  const int nk = K >> 5;
  stage(0, 0);
  for (int kk = 0; kk < nk; ++kk) {
    const int cur = kk & 1;
    __syncthreads();
    if (kk + 1 < nk) stage(cur ^ 1, (kk + 1) << 5);
    bf16x8 af[4], bfr[4];
#pragma unroll
    for (int m = 0; m < 4; ++m) {
      const int row = wr * 64 + m * 16 + lr;
      const int sl = lg ^ (row & 3);
      af[m] = *(const bf16x8*)(&lA[cur][row * 32 + sl * 8]);
    }
#pragma unroll
    for (int n = 0; n < 4; ++n) {
      const int row = wc * 64 + n * 16 + lr;
      const int sl = lg ^ (row & 3);
      bfr[n] = *(const bf16x8*)(&lB[cur][row * 32 + sl * 8]);
    }
#pragma unroll
    for (int m = 0; m < 4; ++m)
#pragma unroll
      for (int n = 0; n < 4; ++n)
        acc[m][n] = mfma16x16(af[m], bfr[n], acc[m][n]);
  }

  const float C = -0.4152410118609203f;   // -log2(10000)/32
  const float QS = 0.125f * 1.44269504088896341f;
  const float R2PI = 0.15915494309189535f;

  if (isqk) {          // q or k block: register-local RoPE pair
    const bool isq = (bcol < 1024);
    const int head = ((bcol + wc * 64) >> 6) & 15;
    u16* dst = isq ? qb : kbuf;
#pragma unroll
    for (int n = 0; n < 2; ++n) {
      const int p = n * 16 + lr;          // pair index; d = 2p
      const float inv = exp2f((float)p * C);
#pragma unroll
      for (int m = 0; m < 4; ++m)
#pragma unroll
        for (int r = 0; r < 4; ++r) {
          const int row = brow + wr * 64 + m * 16 + lg * 4 + r;
          const int t = row & (TSEQ - 1), b = row >> 11;
          const float rev = __builtin_amdgcn_fractf((float)t * inv * R2PI);
          float sn = __builtin_amdgcn_sinf(rev);
          float cs = __builtin_amdgcn_cosf(rev);
          if (isq) { sn *= QS; cs *= QS; }
          const float e = acc[m][n][r];     // even d = 2p
          const float o = acc[m][n + 2][r]; // odd  d = 2p+1
          const u32 pk = pack2bf(e * cs - o * sn, e * sn + o * cs);
          *(u32*)(&dst[(((size_t)(b * 16 + head)) * TSEQ + t) * 64 + 2 * p]) = pk;
        }
    }
  } else {             // v block: transposed write to vbT[bh][64][TSEQ]
    const int head = (((bcol - 2048) + wc * 64) >> 6) & 15;
#pragma unroll
    for (int n = 0; n < 4; ++n) {
      const int d = n * 16 + lr;
#pragma unroll
      for (int m = 0; m < 4; ++m) {
        const int row0 = brow + wr * 64 + m * 16 + lg * 4;
        const int t = row0 & (TSEQ - 1), b = row0 >> 11;
        uint2 pk;
        pk.x = pack2bf(acc[m][n][0], acc[m][n][1]);
        pk.y = pack2bf(acc[m][n][2], acc[m][n][3]);
        *(uint2*)(&vbT[((size_t)(b * 16 + head) * 64 + d) * TSEQ + t]) = pk;
      }
    }
  }
}

// ------------- bf16 GEMM 64x128 tile (fp32 out) — output projection --------
__global__ __launch_bounds__(256, 2) void gemm_bt64(const u16* __restrict__ A,
                                                    const u16* __restrict__ Bm,
                                                    float* __restrict__ Cf,
                                                    int M, int N, int K) {
  __shared__ u16 lA[2][64 * 32];
  __shared__ u16 lB[2][128 * 32];
  const int tid = threadIdx.x;
  const int w = tid >> 6, l = tid & 63;
  const int wr = w >> 1, wc = w & 1;
  int bid = blockIdx.y * gridDim.x + blockIdx.x;
  const int cpx = (gridDim.x * gridDim.y) >> 3;
  bid = (bid & 7) * cpx + (bid >> 3);
  const int bx = bid % gridDim.x, by = bid / gridDim.x;
  const int brow = by * 64, bcol = bx * 128;
  const int lr = l & 15, lg = l >> 4;

  const int srow = l >> 2;
  const int scol = (((l & 3) ^ (srow & 3)) * 8);

  auto stage = [&](int buf, int k0) {
    {
      const int row = w * 16 + srow;
      __builtin_amdgcn_global_load_lds(AS1C(A + (size_t)(brow + row) * K + k0 + scol),
                                       AS3((char*)lA[buf] + w * 1024), 16, 0, 0);
    }
#pragma unroll
    for (int is = 0; is < 2; ++is) {
      const int chunk = w * 2 + is;
      const int row = chunk * 16 + srow;
      __builtin_amdgcn_global_load_lds(AS1C(Bm + (size_t)(bcol + row) * K + k0 + scol),
                                       AS3((char*)lB[buf] + chunk * 1024), 16, 0, 0);
    }
  };

  f32x4 acc[2][4] = {};
  const int nk = K >> 5;
  stage(0, 0);
  for (int kk = 0; kk < nk; ++kk) {
    const int cur = kk & 1;
    __syncthreads();
    if (kk + 1 < nk) stage(cur ^ 1, (kk + 1) << 5);
    bf16x8 af[2], bfr[4];
#pragma unroll
    for (int m = 0; m < 2; ++m) {
      const int row = wr * 32 + m * 16 + lr;
      const int sl = lg ^ (row & 3);
      af[m] = *(const bf16x8*)(&lA[cur][row * 32 + sl * 8]);
    }
#pragma unroll
    for (int n = 0; n < 4; ++n) {
      const int row = wc * 64 + n * 16 + lr;
      const int sl = lg ^ (row & 3);
      bfr[n] = *(const bf16x8*)(&lB[cur][row * 32 + sl * 8]);
    }
#pragma unroll
    for (int m = 0; m < 2; ++m)
#pragma unroll
      for (int n = 0; n < 4; ++n)
        acc[m][n] = mfma16x16(af[m], bfr[n], acc[m][n]);
  }
#pragma unroll
  for (int m = 0; m < 2; ++m)
#pragma unroll
    for (int n = 0; n < 4; ++n)
#pragma unroll
      for (int r = 0; r < 4; ++r) {
        const int row = brow + wr * 32 + m * 16 + lg * 4 + r;
        const int col = bcol + wc * 64 + n * 16 + lr;
        Cf[(size_t)row * N + col] = acc[m][n][r];
      }
}

// ---------------- causal flash attention (R5-proven configuration) --------
__global__ __launch_bounds__(512, 4) void attn_fwd(const u16* __restrict__ qb,
                                                   const u16* __restrict__ kb,
                                                   const u16* __restrict__ vbT,
                                                   u16* __restrict__ ob) {
  __shared__ u16 lK[4][64 * 64];
  __shared__ u16 lV[4][64 * 64];
  __shared__ u16 lP[8][16 * 64];
  const int hw = blockIdx.x;
  const int logical = (hw & 7) * 64 + (hw >> 3);  // 8 XCDs x 64 blocks
  const int bh = logical >> 4;            // 4 consecutive heads per XCD
  const int pair = logical & 15;
  const int b = bh >> 4, h = bh & 15;
  const int tid = threadIdx.x;
  const int w = tid >> 6, l = tid & 63;
  const int g = w >> 2, wq = w & 3;       // kv-group, q-wave within group
  const int lr = l & 15, lg = l >> 4;
  const int srow8 = l >> 3;
  const int scol = ((l & 7) ^ srow8) * 8; // pre-swizzled source col (elems)
  const u16* Kb = kb + (size_t)bh * TSEQ * 64;
  const u16* Vb = vbT + (size_t)bh * 64 * TSEQ;
  u16* lPw = lP[w];

  auto stage = [&](int buf, int kt) {
#pragma unroll
    for (int is = 0; is < 2; ++is) {
      const int chunk = wq * 2 + is;            // 0..7, 1KB each
      const int row = chunk * 8 + srow8;        // 0..63
      __builtin_amdgcn_global_load_lds(AS1C(Kb + (size_t)(kt * 64 + row) * 64 + scol),
                                       AS3((char*)lK[buf] + chunk * 1024), 16, 0, 0);
      __builtin_amdgcn_global_load_lds(AS1C(Vb + (size_t)row * TSEQ + kt * 64 + scol),
                                       AS3((char*)lV[buf] + chunk * 1024), 16, 0, 0);
    }
  };

  for (int half = 0; half < 2; ++half) {
    const int qt = half ? (TSEQ / 64 - 1 - pair) : pair;
    const int q0 = qt * 64;

    bf16x8 qf[2];
    {
      const u16* qp = qb + ((size_t)bh * TSEQ + q0 + wq * 16 + lr) * 64 + lg * 8;
      qf[0] = *(const bf16x8*)qp;
      qf[1] = *(const bf16x8*)(qp + 32);
    }

    f32x4 oacc[4] = {};
    float lsum = 0.f;

    const int nt = qt + 1;
    const int nit = (nt + 1) >> 1;
    const int ql = wq * 16 + lr;

    __syncthreads();                 // LDS safe to overwrite (prev half done)
    if (g < nt) stage(g * 2, g);
    for (int it = 0; it < nit; ++it) {
      const int cur = it & 1;
      __syncthreads();               // staged buf[cur] visible to whole group
      const int ktn = 2 * (it + 1) + g;
      if (ktn < nt) stage(g * 2 + (cur ^ 1), ktn);
      const int kt = 2 * it + g;
      if (kt < nt) {
        const u16* Kc = lK[g * 2 + cur];
        const u16* Vc = lV[g * 2 + cur];

        // S^T = K Q^T: lane holds S[q=lr][kv = n*16 + lg*4 + r] (log2 domain)
        f32x4 s[4] = {};
        __builtin_amdgcn_s_setprio(1);
#pragma unroll
        for (int n = 0; n < 4; ++n) {
          const int row = n * 16 + lr;
#pragma unroll
          for (int ks = 0; ks < 2; ++ks) {
            const int sl = (ks * 4 + lg) ^ (row & 7);
            bf16x8 kf = *(const bf16x8*)(&Kc[row * 64 + sl * 8]);
            s[n] = mfma16x16(kf, qf[ks], s[n]);
          }
        }
        __builtin_amdgcn_s_setprio(0);

        // P = exp2(s) raw; masked entries zeroed; per-lane partial sums.
        const bool diag = (kt == qt);
#pragma unroll
        for (int n = 0; n < 4; ++n) {
          float pv[4];
#pragma unroll
          for (int r = 0; r < 4; ++r) {
            float p = __builtin_amdgcn_exp2f(s[n][r]);
            if (diag && (n * 16 + lg * 4 + r > ql)) p = 0.f;
            pv[r] = p;
            lsum += p;
          }
          const u32 w0 = pack2bf(pv[0], pv[1]);
          const u32 w1 = pack2bf(pv[2], pv[3]);
          const int phys = (n * 2 + (lg >> 1)) ^ (lr & 7);
          uint2 pk; pk.x = w0; pk.y = w1;
          *(uint2*)(&lPw[lr * 64 + phys * 8 + (lg & 1) * 4]) = pk;
        }

        // O^T += V P^T: lane holds O[q=lr][d = n*16 + lg*4 + r]
        bf16x8 pf[2];
#pragma unroll
        for (int ks = 0; ks < 2; ++ks) {
          const int phys = (ks * 4 + lg) ^ (lr & 7);
          pf[ks] = *(const bf16x8*)(&lPw[lr * 64 + phys * 8]);
        }
        __builtin_amdgcn_s_setprio(1);
#pragma unroll
        for (int n = 0; n < 4; ++n) {
          const int row = n * 16 + lr;
#pragma unroll
          for (int ks = 0; ks < 2; ++ks) {
            const int sl = (ks * 4 + lg) ^ (row & 7);
            bf16x8 vf = *(const bf16x8*)(&Vc[row * 64 + sl * 8]);
            oacc[n] = mfma16x16(vf, pf[ks], oacc[n]);
          }
        }
        __builtin_amdgcn_s_setprio(0);
      }
    }

    // row-total of this group's partial sums (single reduction per q-tile)
    lsum += __shfl_xor(lsum, 16);
    lsum += __shfl_xor(lsum, 32);

    // merge the two groups' (O, l) through LDS — no exp scaling needed
    __syncthreads();                  // all compute done; K/V LDS reusable
    float* mO = (float*)&lK[0][0];    // 4 waves x 1024 f32 = 16KB
    float* mL = (float*)&lV[0][0];    // 4 waves x 16 f32
    if (g == 1) {
#pragma unroll
      for (int n = 0; n < 4; ++n)
#pragma unroll
        for (int r = 0; r < 4; ++r) {
          const int d = n * 16 + lg * 4 + r;
          mO[wq * 1024 + d * 16 + lr] = oacc[n][r];
        }
      if (lg == 0) mL[wq * 16 + lr] = lsum;
    }
    __syncthreads();
    if (g == 0) {
      const float rl = 1.f / (lsum + mL[wq * 16 + lr]);
      const int q = q0 + wq * 16 + lr;
#pragma unroll
      for (int n = 0; n < 4; ++n) {
        ushort4 ov;
#pragma unroll
        for (int r = 0; r < 4; ++r) {
          const int d = n * 16 + lg * 4 + r;
          const float o = oacc[n][r] + mO[wq * 1024 + d * 16 + lr];
          ((u16*)&ov)[r] = f2bf(o * rl);
        }
        *(ushort4*)(&ob[(size_t)(b * TSEQ + q) * DM + h * 64 + n * 16 + lg * 4]) = ov;
      }
    }
  }
}

// ---------------- launch ----------------
extern "C" void kernel_launch(void* const* d_in, const int* in_sizes, int n_in,
                              void* d_out, int out_size, void* d_ws, size_t ws_size,
                              hipStream_t stream) {
  const float* x    = (const float*)d_in[0];
  const float* Wqkv = (const float*)d_in[1];
  const float* Wo   = (const float*)d_in[2];
  float* out = (float*)d_out;

  char* ws = (char*)d_ws;
  u16* xb    = (u16*)ws; ws += (size_t)MROWS * DM * 2;
  u16* wqkvb = (u16*)ws; ws += (size_t)3 * DM * DM * 2;
  u16* wob   = (u16*)ws; ws += (size_t)DM * DM * 2;
  u16* qb    = (u16*)ws; ws += (size_t)BB * NHEADS * TSEQ * HDIM * 2;
  u16* kb    = (u16*)ws; ws += (size_t)BB * NHEADS * TSEQ * HDIM * 2;
  u16* vbT   = (u16*)ws; ws += (size_t)BB * NHEADS * TSEQ * HDIM * 2;
  u16* ob    = (u16*)ws; ws += (size_t)MROWS * DM * 2;

  cast_all<<<2048, 256, 0, stream>>>(x, Wqkv, Wo, xb, wqkvb, wob);

  gemm_qkv<<<dim3(3 * DM / 128, MROWS / 128), 256, 0, stream>>>(
      xb, wqkvb, qb, kb, vbT, MROWS, 3 * DM, DM);

  attn_fwd<<<512, 512, 0, stream>>>(qb, kb, vbT, ob);

  gemm_bt64<<<dim3(DM / 128, MROWS / 64), 256, 0, stream>>>(
      ob, wob, out, MROWS, DM, DM);
}

// Round 18
// 97.724 us; speedup vs baseline: 1.4250x; 1.0057x over previous
//
#include <hip/hip_runtime.h>
#include <hip/hip_bf16.h>
#include <cstdint>

#define NHEADS 16
#define HDIM 64
#define BB 2
#define TSEQ 2048
#define DM 1024
#define MROWS (BB*TSEQ)   // 4096

typedef unsigned short u16;
typedef unsigned int u32;
typedef __bf16 bf16x8 __attribute__((ext_vector_type(8)));
typedef float f32x4 __attribute__((ext_vector_type(4)));

#define AS1C(p) ((const __attribute__((address_space(1))) u32*)(p))
#define AS3(p)  ((__attribute__((address_space(3))) u32*)(p))

static __device__ __forceinline__ u16 f2bf(float f) {
  return __builtin_bit_cast(u16, __float2bfloat16(f));
}
static __device__ __forceinline__ float bf2f(u16 u) {
  return __bfloat162float(__builtin_bit_cast(__hip_bfloat16, u));
}
// pack two non-NaN floats to bf16 pair (round-half-up, max rel err 2^-8)
static __device__ __forceinline__ u32 pack2bf(float a, float b) {
  const u32 ua = __builtin_bit_cast(u32, a) + 0x8000u;
  const u32 ub = __builtin_bit_cast(u32, b) + 0x8000u;
  return (ua >> 16) | (ub & 0xFFFF0000u);
}
static __device__ __forceinline__ f32x4 mfma16x16(bf16x8 a, bf16x8 b, f32x4 c) {
  return __builtin_amdgcn_mfma_f32_16x16x32_bf16(a, b, c, 0, 0, 0);
}

// ---------------- fused cast fp32 -> bf16 for x, W_qkv, W_o ----------------
#define N4_X   (MROWS * DM / 4)
#define N4_WQ  (3 * DM * DM / 4)
#define N4_WO  (DM * DM / 4)
__global__ __launch_bounds__(256) void cast_all(const float* __restrict__ x,
                                                const float* __restrict__ wq,
                                                const float* __restrict__ wo,
                                                u16* __restrict__ xb,
                                                u16* __restrict__ wqb,
                                                u16* __restrict__ wob) {
  int i = blockIdx.x * 256 + threadIdx.x;
  const int stride = gridDim.x * 256;
  for (; i < N4_X + N4_WQ + N4_WO; i += stride) {
    const float4* src; u16* dst; int j;
    if (i < N4_X)            { src = (const float4*)x;  dst = xb;  j = i; }
    else if (i < N4_X + N4_WQ) { src = (const float4*)wq; dst = wqb; j = i - N4_X; }
    else                     { src = (const float4*)wo; dst = wob; j = i - N4_X - N4_WQ; }
    float4 v = src[j];
    ushort4 o;
    o.x = f2bf(v.x); o.y = f2bf(v.y); o.z = f2bf(v.z); o.w = f2bf(v.w);
    ((ushort4*)dst)[j] = o;
  }
}

// ------- GEMM1 fused: qkv = x @ Wqkv^T, epilogue does RoPE + reshape -------
// 128x128 tile, 2-phase double-buffer. B-rows permuted at the staging source
// for q/k blocks so the RoPE pair (2p,2p+1) is register-local (frag n, n+2).
// LDS swizzle: rows are 64B (bank wrap = 2 rows), so the slot XOR must use
// (row>>1)&3 — the old (row&3) left lanes {0,4,8,12} on the same banks
// (4-way conflict, 1.58x per ds_read_b128). Source swizzle matches:
// scol = ((l&3) ^ ((l>>3)&3)) * 8.
__global__ __launch_bounds__(256, 4) void gemm_qkv(const u16* __restrict__ A,
                                                   const u16* __restrict__ Bm,
                                                   u16* __restrict__ qb,
                                                   u16* __restrict__ kbuf,
                                                   u16* __restrict__ vbT,
                                                   int M, int N, int K) {
  __shared__ u16 lA[2][128 * 32];
  __shared__ u16 lB[2][128 * 32];
  const int tid = threadIdx.x;
  const int w = tid >> 6, l = tid & 63;
  const int wr = w >> 1, wc = w & 1;
  int bid = blockIdx.y * gridDim.x + blockIdx.x;
  const int cpx = (gridDim.x * gridDim.y) >> 3;
  bid = (bid & 7) * cpx + (bid >> 3);
  const int bx = bid % gridDim.x, by = bid / gridDim.x;
  const int brow = by * 128, bcol = bx * 128;
  const int lr = l & 15, lg = l >> 4;
  const bool isqk = (bcol < 2048);

  const int srow = l >> 2;
  const int scol = (((l & 3) ^ ((l >> 3) & 3)) * 8);  // bank-safe source swz

  auto stage = [&](int buf, int k0) {
#pragma unroll
    for (int is = 0; is < 2; ++is) {
      const int chunk = w * 2 + is;
      const int row = chunk * 16 + srow;
      __builtin_amdgcn_global_load_lds(AS1C(A + (size_t)(brow + row) * K + k0 + scol),
                                       AS3((char*)lA[buf] + chunk * 1024), 16, 0, 0);
      int prow = row;
      if (isqk) {
        const int r63 = row & 63;
        prow = (row & 64) | ((r63 < 32) ? (2 * r63) : (2 * (r63 - 32) + 1));
      }
      __builtin_amdgcn_global_load_lds(AS1C(Bm + (size_t)(bcol + prow) * K + k0 + scol),
                                       AS3((char*)lB[buf] + chunk * 1024), 16, 0, 0);
    }
  };

  f32x4 acc[4][4] = {};
  const int nk = K >> 5;
  stage(0, 0);
  for (int kk = 0; kk < nk; ++kk) {
    const int cur = kk & 1;
    __syncthreads();
    if (kk + 1 < nk) stage(cur ^ 1, (kk + 1) << 5);
    bf16x8 af[4], bfr[4];
#pragma unroll
    for (int m = 0; m < 4; ++m) {
      const int row = wr * 64 + m * 16 + lr;
      const int sl = lg ^ ((row >> 1) & 3);
      af[m] = *(const bf16x8*)(&lA[cur][row * 32 + sl * 8]);
    }
#pragma unroll
    for (int n = 0; n < 4; ++n) {
      const int row = wc * 64 + n * 16 + lr;
      const int sl = lg ^ ((row >> 1) & 3);
      bfr[n] = *(const bf16x8*)(&lB[cur][row * 32 + sl * 8]);
    }
#pragma unroll
    for (int m = 0; m < 4; ++m)
#pragma unroll
      for (int n = 0; n < 4; ++n)
        acc[m][n] = mfma16x16(af[m], bfr[n], acc[m][n]);
  }

  const float C = -0.4152410118609203f;   // -log2(10000)/32
  const float QS = 0.125f * 1.44269504088896341f;
  const float R2PI = 0.15915494309189535f;

  if (isqk) {          // q or k block: register-local RoPE pair
    const bool isq = (bcol < 1024);
    const int head = ((bcol + wc * 64) >> 6) & 15;
    u16* dst = isq ? qb : kbuf;
#pragma unroll
    for (int n = 0; n < 2; ++n) {
      const int p = n * 16 + lr;          // pair index; d = 2p
      const float inv = exp2f((float)p * C);
#pragma unroll
      for (int m = 0; m < 4; ++m)
#pragma unroll
        for (int r = 0; r < 4; ++r) {
          const int row = brow + wr * 64 + m * 16 + lg * 4 + r;
          const int t = row & (TSEQ - 1), b = row >> 11;
          const float rev = __builtin_amdgcn_fractf((float)t * inv * R2PI);
          float sn = __builtin_amdgcn_sinf(rev);
          float cs = __builtin_amdgcn_cosf(rev);
          if (isq) { sn *= QS; cs *= QS; }
          const float e = acc[m][n][r];     // even d = 2p
          const float o = acc[m][n + 2][r]; // odd  d = 2p+1
          const u32 pk = pack2bf(e * cs - o * sn, e * sn + o * cs);
          *(u32*)(&dst[(((size_t)(b * 16 + head)) * TSEQ + t) * 64 + 2 * p]) = pk;
        }
    }
  } else {             // v block: transposed write to vbT[bh][64][TSEQ]
    const int head = (((bcol - 2048) + wc * 64) >> 6) & 15;
#pragma unroll
    for (int n = 0; n < 4; ++n) {
      const int d = n * 16 + lr;
#pragma unroll
      for (int m = 0; m < 4; ++m) {
        const int row0 = brow + wr * 64 + m * 16 + lg * 4;
        const int t = row0 & (TSEQ - 1), b = row0 >> 11;
        uint2 pk;
        pk.x = pack2bf(acc[m][n][0], acc[m][n][1]);
        pk.y = pack2bf(acc[m][n][2], acc[m][n][3]);
        *(uint2*)(&vbT[((size_t)(b * 16 + head) * 64 + d) * TSEQ + t]) = pk;
      }
    }
  }
}

// ------------- bf16 GEMM 64x128 tile (fp32 out) — output projection --------
// Same bank-safe swizzle as gemm_qkv ((row>>1)&3 with matching source).
__global__ __launch_bounds__(256, 2) void gemm_bt64(const u16* __restrict__ A,
                                                    const u16* __restrict__ Bm,
                                                    float* __restrict__ Cf,
                                                    int M, int N, int K) {
  __shared__ u16 lA[2][64 * 32];
  __shared__ u16 lB[2][128 * 32];
  const int tid = threadIdx.x;
  const int w = tid >> 6, l = tid & 63;
  const int wr = w >> 1, wc = w & 1;
  int bid = blockIdx.y * gridDim.x + blockIdx.x;
  const int cpx = (gridDim.x * gridDim.y) >> 3;
  bid = (bid & 7) * cpx + (bid >> 3);
  const int bx = bid % gridDim.x, by = bid / gridDim.x;
  const int brow = by * 64, bcol = bx * 128;
  const int lr = l & 15, lg = l >> 4;

  const int srow = l >> 2;
  const int scol = (((l & 3) ^ ((l >> 3) & 3)) * 8);

  auto stage = [&](int buf, int k0) {
    {
      const int row = w * 16 + srow;
      __builtin_amdgcn_global_load_lds(AS1C(A + (size_t)(brow + row) * K + k0 + scol),
                                       AS3((char*)lA[buf] + w * 1024), 16, 0, 0);
    }
#pragma unroll
    for (int is = 0; is < 2; ++is) {
      const int chunk = w * 2 + is;
      const int row = chunk * 16 + srow;
      __builtin_amdgcn_global_load_lds(AS1C(Bm + (size_t)(bcol + row) * K + k0 + scol),
                                       AS3((char*)lB[buf] + chunk * 1024), 16, 0, 0);
    }
  };

  f32x4 acc[2][4] = {};
  const int nk = K >> 5;
  stage(0, 0);
  for (int kk = 0; kk < nk; ++kk) {
    const int cur = kk & 1;
    __syncthreads();
    if (kk + 1 < nk) stage(cur ^ 1, (kk + 1) << 5);
    bf16x8 af[2], bfr[4];
#pragma unroll
    for (int m = 0; m < 2; ++m) {
      const int row = wr * 32 + m * 16 + lr;
      const int sl = lg ^ ((row >> 1) & 3);
      af[m] = *(const bf16x8*)(&lA[cur][row * 32 + sl * 8]);
    }
#pragma unroll
    for (int n = 0; n < 4; ++n) {
      const int row = wc * 64 + n * 16 + lr;
      const int sl = lg ^ ((row >> 1) & 3);
      bfr[n] = *(const bf16x8*)(&lB[cur][row * 32 + sl * 8]);
    }
#pragma unroll
    for (int m = 0; m < 2; ++m)
#pragma unroll
      for (int n = 0; n < 4; ++n)
        acc[m][n] = mfma16x16(af[m], bfr[n], acc[m][n]);
  }
#pragma unroll
  for (int m = 0; m < 2; ++m)
#pragma unroll
    for (int n = 0; n < 4; ++n)
#pragma unroll
      for (int r = 0; r < 4; ++r) {
        const int row = brow + wr * 32 + m * 16 + lg * 4 + r;
        const int col = bcol + wc * 64 + n * 16 + lr;
        Cf[(size_t)row * N + col] = acc[m][n][r];
      }
}

// ---------------- causal flash attention (R5-proven configuration) --------
__global__ __launch_bounds__(512, 4) void attn_fwd(const u16* __restrict__ qb,
                                                   const u16* __restrict__ kb,
                                                   const u16* __restrict__ vbT,
                                                   u16* __restrict__ ob) {
  __shared__ u16 lK[4][64 * 64];
  __shared__ u16 lV[4][64 * 64];
  __shared__ u16 lP[8][16 * 64];
  const int hw = blockIdx.x;
  const int logical = (hw & 7) * 64 + (hw >> 3);  // 8 XCDs x 64 blocks
  const int bh = logical >> 4;            // 4 consecutive heads per XCD
  const int pair = logical & 15;
  const int b = bh >> 4, h = bh & 15;
  const int tid = threadIdx.x;
  const int w = tid >> 6, l = tid & 63;
  const int g = w >> 2, wq = w & 3;       // kv-group, q-wave within group
  const int lr = l & 15, lg = l >> 4;
  const int srow8 = l >> 3;
  const int scol = ((l & 7) ^ srow8) * 8; // pre-swizzled source col (elems)
  const u16* Kb = kb + (size_t)bh * TSEQ * 64;
  const u16* Vb = vbT + (size_t)bh * 64 * TSEQ;
  u16* lPw = lP[w];

  auto stage = [&](int buf, int kt) {
#pragma unroll
    for (int is = 0; is < 2; ++is) {
      const int chunk = wq * 2 + is;            // 0..7, 1KB each
      const int row = chunk * 8 + srow8;        // 0..63
      __builtin_amdgcn_global_load_lds(AS1C(Kb + (size_t)(kt * 64 + row) * 64 + scol),
                                       AS3((char*)lK[buf] + chunk * 1024), 16, 0, 0);
      __builtin_amdgcn_global_load_lds(AS1C(Vb + (size_t)row * TSEQ + kt * 64 + scol),
                                       AS3((char*)lV[buf] + chunk * 1024), 16, 0, 0);
    }
  };

  for (int half = 0; half < 2; ++half) {
    const int qt = half ? (TSEQ / 64 - 1 - pair) : pair;
    const int q0 = qt * 64;

    bf16x8 qf[2];
    {
      const u16* qp = qb + ((size_t)bh * TSEQ + q0 + wq * 16 + lr) * 64 + lg * 8;
      qf[0] = *(const bf16x8*)qp;
      qf[1] = *(const bf16x8*)(qp + 32);
    }

    f32x4 oacc[4] = {};
    float lsum = 0.f;

    const int nt = qt + 1;
    const int nit = (nt + 1) >> 1;
    const int ql = wq * 16 + lr;

    __syncthreads();                 // LDS safe to overwrite (prev half done)
    if (g < nt) stage(g * 2, g);
    for (int it = 0; it < nit; ++it) {
      const int cur = it & 1;
      __syncthreads();               // staged buf[cur] visible to whole group
      const int ktn = 2 * (it + 1) + g;
      if (ktn < nt) stage(g * 2 + (cur ^ 1), ktn);
      const int kt = 2 * it + g;
      if (kt < nt) {
        const u16* Kc = lK[g * 2 + cur];
        const u16* Vc = lV[g * 2 + cur];

        // S^T = K Q^T: lane holds S[q=lr][kv = n*16 + lg*4 + r] (log2 domain)
        f32x4 s[4] = {};
        __builtin_amdgcn_s_setprio(1);
#pragma unroll
        for (int n = 0; n < 4; ++n) {
          const int row = n * 16 + lr;
#pragma unroll
          for (int ks = 0; ks < 2; ++ks) {
            const int sl = (ks * 4 + lg) ^ (row & 7);
            bf16x8 kf = *(const bf16x8*)(&Kc[row * 64 + sl * 8]);
            s[n] = mfma16x16(kf, qf[ks], s[n]);
          }
        }
        __builtin_amdgcn_s_setprio(0);

        // P = exp2(s) raw; masked entries zeroed; per-lane partial sums.
        const bool diag = (kt == qt);
#pragma unroll
        for (int n = 0; n < 4; ++n) {
          float pv[4];
#pragma unroll
          for (int r = 0; r < 4; ++r) {
            float p = __builtin_amdgcn_exp2f(s[n][r]);
            if (diag && (n * 16 + lg * 4 + r > ql)) p = 0.f;
            pv[r] = p;
            lsum += p;
          }
          const u32 w0 = pack2bf(pv[0], pv[1]);
          const u32 w1 = pack2bf(pv[2], pv[3]);
          const int phys = (n * 2 + (lg >> 1)) ^ (lr & 7);
          uint2 pk; pk.x = w0; pk.y = w1;
          *(uint2*)(&lPw[lr * 64 + phys * 8 + (lg & 1) * 4]) = pk;
        }

        // O^T += V P^T: lane holds O[q=lr][d = n*16 + lg*4 + r]
        bf16x8 pf[2];
#pragma unroll
        for (int ks = 0; ks < 2; ++ks) {
          const int phys = (ks * 4 + lg) ^ (lr & 7);
          pf[ks] = *(const bf16x8*)(&lPw[lr * 64 + phys * 8]);
        }
        __builtin_amdgcn_s_setprio(1);
#pragma unroll
        for (int n = 0; n < 4; ++n) {
          const int row = n * 16 + lr;
#pragma unroll
          for (int ks = 0; ks < 2; ++ks) {
            const int sl = (ks * 4 + lg) ^ (row & 7);
            bf16x8 vf = *(const bf16x8*)(&Vc[row * 64 + sl * 8]);
            oacc[n] = mfma16x16(vf, pf[ks], oacc[n]);
          }
        }
        __builtin_amdgcn_s_setprio(0);
      }
    }

    // row-total of this group's partial sums (single reduction per q-tile)
    lsum += __shfl_xor(lsum, 16);
    lsum += __shfl_xor(lsum, 32);

    // merge the two groups' (O, l) through LDS — no exp scaling needed
    __syncthreads();                  // all compute done; K/V LDS reusable
    float* mO = (float*)&lK[0][0];    // 4 waves x 1024 f32 = 16KB
    float* mL = (float*)&lV[0][0];    // 4 waves x 16 f32
    if (g == 1) {
#pragma unroll
      for (int n = 0; n < 4; ++n)
#pragma unroll
        for (int r = 0; r < 4; ++r) {
          const int d = n * 16 + lg * 4 + r;
          mO[wq * 1024 + d * 16 + lr] = oacc[n][r];
        }
      if (lg == 0) mL[wq * 16 + lr] = lsum;
    }
    __syncthreads();
    if (g == 0) {
      const float rl = 1.f / (lsum + mL[wq * 16 + lr]);
      const int q = q0 + wq * 16 + lr;
#pragma unroll
      for (int n = 0; n < 4; ++n) {
        ushort4 ov;
#pragma unroll
        for (int r = 0; r < 4; ++r) {
          const int d = n * 16 + lg * 4 + r;
          const float o = oacc[n][r] + mO[wq * 1024 + d * 16 + lr];
          ((u16*)&ov)[r] = f2bf(o * rl);
        }
        *(ushort4*)(&ob[(size_t)(b * TSEQ + q) * DM + h * 64 + n * 16 + lg * 4]) = ov;
      }
    }
  }
}

// ---------------- launch ----------------
extern "C" void kernel_launch(void* const* d_in, const int* in_sizes, int n_in,
                              void* d_out, int out_size, void* d_ws, size_t ws_size,
                              hipStream_t stream) {
  const float* x    = (const float*)d_in[0];
  const float* Wqkv = (const float*)d_in[1];
  const float* Wo   = (const float*)d_in[2];
  float* out = (float*)d_out;

  char* ws = (char*)d_ws;
  u16* xb    = (u16*)ws; ws += (size_t)MROWS * DM * 2;
  u16* wqkvb = (u16*)ws; ws += (size_t)3 * DM * DM * 2;
  u16* wob   = (u16*)ws; ws += (size_t)DM * DM * 2;
  u16* qb    = (u16*)ws; ws += (size_t)BB * NHEADS * TSEQ * HDIM * 2;
  u16* kb    = (u16*)ws; ws += (size_t)BB * NHEADS * TSEQ * HDIM * 2;
  u16* vbT   = (u16*)ws; ws += (size_t)BB * NHEADS * TSEQ * HDIM * 2;
  u16* ob    = (u16*)ws; ws += (size_t)MROWS * DM * 2;

  cast_all<<<2048, 256, 0, stream>>>(x, Wqkv, Wo, xb, wqkvb, wob);

  gemm_qkv<<<dim3(3 * DM / 128, MROWS / 128), 256, 0, stream>>>(
      xb, wqkvb, qb, kb, vbT, MROWS, 3 * DM, DM);

  attn_fwd<<<512, 512, 0, stream>>>(qb, kb, vbT, ob);

  gemm_bt64<<<dim3(DM / 128, MROWS / 64), 256, 0, stream>>>(
      ob, wob, out, MROWS, DM, DM);
}